// Round 11
// baseline (148.026 us; speedup 1.0000x reference)
//
#include <hip/hip_runtime.h>
#include <hip/hip_bf16.h>
#include <math.h>

#define NPTS   16384
#define NCH    8
#define MT     64
#define LSTR   264   // act row stride (ushort)
#define SEG    16384 // fixed bucket segment per chart
#define PSEG   2048  // points per scatter sub-segment

typedef short bf16x8 __attribute__((ext_vector_type(8)));
typedef float f32x4  __attribute__((ext_vector_type(4)));

__device__ __forceinline__ float bf2f(unsigned short u){
  union { unsigned int i; float f; } v; v.i = ((unsigned int)u) << 16; return v.f;
}
__device__ __forceinline__ unsigned short f2bf(float f){
  union { float f; unsigned int i; } v; v.f = f;
  unsigned int x = v.i;
  return (unsigned short)((x + 0x7fffu + ((x >> 16) & 1u)) >> 16); // RNE
}

// ---- prep: transpose to k8-major + atomic-free bucketing (unchanged r10) --

__global__ __launch_bounds__(256) void prep_k(
    const float* __restrict__ Wh, const float* __restrict__ W0,
    const int* __restrict__ midx,
    unsigned short* __restrict__ Wth, unsigned short* __restrict__ Wt0,
    int* __restrict__ segcnt, int* __restrict__ bucket){
  int bid = blockIdx.x, tid = threadIdx.x;
  if (bid < 192){
    __shared__ __align__(16) unsigned short tile[64 * LSTR];
    int mat = bid >> 2, ck = bid & 3;
    const float* src = Wh + (size_t)mat * 65536 + (size_t)ck * 64 * 256;
    int r = tid >> 2, seg = (tid & 3) * 64;
    const float* sp = &src[r * 256 + seg];
    #pragma unroll
    for (int j8 = 0; j8 < 8; j8++){
      float4 f0 = *(const float4*)&sp[j8 * 8];
      float4 f1 = *(const float4*)&sp[j8 * 8 + 4];
      __align__(16) unsigned short t8[8];
      t8[0]=f2bf(f0.x); t8[1]=f2bf(f0.y); t8[2]=f2bf(f0.z); t8[3]=f2bf(f0.w);
      t8[4]=f2bf(f1.x); t8[5]=f2bf(f1.y); t8[6]=f2bf(f1.z); t8[7]=f2bf(f1.w);
      *(uint4*)&tile[r * LSTR + seg + j8 * 8] = *(const uint4*)t8;
    }
    __syncthreads();
    unsigned short* dst = Wth + (size_t)mat * 65536 + (size_t)ck * 16384;
    #pragma unroll
    for (int it = 0; it < 8; it++){
      int s = it * 256 + tid;
      int k8l = s >> 8, n = s & 255;
      __align__(16) unsigned short t8[8];
      #pragma unroll
      for (int j = 0; j < 8; j++) t8[j] = tile[(k8l * 8 + j) * LSTR + n];
      *(uint4*)&dst[(size_t)s * 8] = *(const uint4*)t8;
    }
  } else if (bid < 200){
    int c = bid - 192;
    #pragma unroll
    for (int it = 0; it < 4; it++){
      int s = it * 256 + tid;
      int k8 = s >> 8, n = s & 255;
      __align__(16) unsigned short t8[8];
      #pragma unroll
      for (int j = 0; j < 8; j++){
        int k = k8 * 8 + j;
        t8[j] = (k < 29) ? f2bf(W0[(c * 29 + k) * 256 + n]) : (unsigned short)0;
      }
      *(uint4*)&Wt0[(size_t)c * 8192 + (size_t)s * 8] = *(const uint4*)t8;
    }
  } else {
    __shared__ int cur[NCH];
    int sb = bid - 200;
    int lane = tid & 63;
    if (tid < NCH) cur[tid] = 0;
    __syncthreads();
    for (int it = 0; it < 8; it++){
      int i = sb * PSEG + it * 256 + tid;
      int c = midx[i];
      #pragma unroll
      for (int cc = 0; cc < NCH; cc++){
        unsigned long long m = __ballot(c == cc);
        if (!m) continue;
        int leader = (int)(__ffsll((long long)m) - 1);
        int wb = 0;
        if (lane == leader) wb = atomicAdd(&cur[cc], (int)__popcll(m));
        wb = __shfl(wb, leader);
        if (c == cc){
          int rk = (int)__popcll(m & ((1ull << lane) - 1));
          bucket[cc * SEG + sb * PSEG + wb + rk] = i;
        }
      }
    }
    __syncthreads();
    if (tid < NCH) segcnt[sb * NCH + tid] = cur[tid];
  }
}

// ---- main fused MLP: double register slab, software-pipelined layers ------

__global__ __launch_bounds__(256, 1) void mlp_k(
    const float* __restrict__ x,
    const float* __restrict__ proc,
    const float* __restrict__ b0,
    const float* __restrict__ bh,
    const float* __restrict__ Wl,
    const float* __restrict__ bl,
    const unsigned short* __restrict__ Wt0,
    const unsigned short* __restrict__ Wth,
    const int* __restrict__ segcnt,
    const int* __restrict__ bucket,
    float* __restrict__ out)
{
  __shared__ __align__(16) unsigned short actA[MT * LSTR];
  __shared__ __align__(16) unsigned short actB[MT * LSTR];
  __shared__ float biasb[7 * 256];
  __shared__ float wlb[512];
  __shared__ int ridx[MT];

  int chart = blockIdx.x & 7;     // XCD swizzle: chart c pinned to XCD c
  int tile  = blockIdx.x >> 3;

  int pre[9];
  pre[0] = 0;
  #pragma unroll
  for (int s = 0; s < 8; s++) pre[s + 1] = pre[s] + segcnt[s * NCH + chart];
  int total = pre[8];
  int cnt = total - tile * MT;
  if (cnt <= 0) return;
  if (cnt > MT) cnt = MT;

  int tid  = threadIdx.x;
  int lane = tid & 63;
  int wv   = tid >> 6;
  int l15  = lane & 15;
  int quad = lane >> 4;
  int cb   = wv * 64;             // wave's output-column base

  f32x4 acc[4][4];
  const f32x4 zz = {0.f, 0.f, 0.f, 0.f};
  bf16x8 bregA[8][4], bregB[8][4];
  bf16x8 b0r[4];

  // early-issue: layer-0 B and layer-1 slab (covered by PE sinf/cosf below)
  {
    const unsigned short* W0p = Wt0 + chart * 8192;
    #pragma unroll
    for (int nt = 0; nt < 4; nt++)
      b0r[nt] = *(const bf16x8*)&W0p[(size_t)(quad * 256 + cb + nt * 16 + l15) * 8];
    const unsigned short* w1 = Wth + ((size_t)(chart * 6) << 16);
    #pragma unroll
    for (int kk = 0; kk < 8; kk++)
      #pragma unroll
      for (int nt = 0; nt < 4; nt++)
        bregA[kk][nt] = *(const bf16x8*)
            &w1[(size_t)((kk * 4 + quad) * 256 + cb + nt * 16 + l15) * 8];
  }

  // stage biases + Wl
  biasb[tid] = b0[chart * 256 + tid];
  #pragma unroll
  for (int j = 0; j < 6; j++)
    biasb[(j + 1) * 256 + tid] = bh[(chart * 6 + j) * 256 + tid];
  wlb[tid]       = Wl[chart * 512 + tid];
  wlb[256 + tid] = Wl[chart * 512 + 256 + tid];

  // positional encoding -> actA
  if (tid < MT){
    int row = tid;
    int g = -1;
    if (row < cnt){
      int r = tile * MT + row;
      int sb = 0, off = 0;
      #pragma unroll
      for (int s = 0; s < 8; s++)
        if (r >= pre[s]){ sb = s; off = r - pre[s]; }
      g = bucket[chart * SEG + sb * PSEG + off];
    }
    ridx[row] = g;
    unsigned short* rowp = &actA[row * LSTR];
    if (g >= 0){
      float xv0 = x[g*3+0], xv1 = x[g*3+1], xv2 = x[g*3+2];
      rowp[0] = f2bf(xv0); rowp[1] = f2bf(xv1); rowp[2] = f2bf(xv2);
      #pragma unroll
      for (int d = 1; d <= 4; d++){
        float s = (float)(1 << d) * 3.14159265358979323846f;
        int o = 3 + (d - 1) * 6;
        rowp[o+0] = f2bf(sinf(s*xv0)); rowp[o+1] = f2bf(sinf(s*xv1)); rowp[o+2] = f2bf(sinf(s*xv2));
        rowp[o+3] = f2bf(cosf(s*xv0)); rowp[o+4] = f2bf(cosf(s*xv1)); rowp[o+5] = f2bf(cosf(s*xv2));
      }
      rowp[27] = f2bf(proc[0]); rowp[28] = f2bf(proc[1]);
      rowp[29] = 0; rowp[30] = 0; rowp[31] = 0;
    } else {
      #pragma unroll
      for (int k = 0; k < 32; k++) rowp[k] = 0;
    }
  }
  __syncthreads();

  // Layer 0: (64x32)@(32x256)
  {
    #pragma unroll
    for (int mt = 0; mt < 4; mt++){
      bf16x8 a0 = *(const bf16x8*)&actA[(mt * 16 + l15) * LSTR + quad * 8];
      #pragma unroll
      for (int nt = 0; nt < 4; nt++)
        acc[mt][nt] = __builtin_amdgcn_mfma_f32_16x16x32_bf16(a0, b0r[nt], zz, 0, 0, 0);
    }
    #pragma unroll
    for (int nt = 0; nt < 4; nt++){
      int col = cb + nt * 16 + l15;
      float bias = biasb[col];
      #pragma unroll
      for (int mt = 0; mt < 4; mt++)
        #pragma unroll
        for (int r = 0; r < 4; r++){
          float v = acc[mt][nt][r] + bias;
          v = v > 0.f ? v : 0.f;
          actB[(mt * 16 + quad * 4 + r) * LSTR + col] = f2bf(v);
        }
    }
    asm volatile("s_waitcnt lgkmcnt(0)\n\ts_barrier" ::: "memory");
  }

  // Layer body: prefetch layer (L+1)'s slab into NXT, compute with CUR.
  // Trailing asm barrier (memory clobber) fences loads into their layer slot.
#define LAYER(L, CUR, NXT, AIN, AOUT, PF)                                      \
  {                                                                            \
    if (PF){                                                                   \
      const unsigned short* wn = Wth + ((size_t)(chart * 6 + (L)) << 16);      \
      _Pragma("unroll")                                                        \
      for (int kk = 0; kk < 8; kk++)                                           \
        _Pragma("unroll")                                                      \
        for (int nt = 0; nt < 4; nt++)                                         \
          NXT[kk][nt] = *(const bf16x8*)                                       \
              &wn[(size_t)((kk * 4 + quad) * 256 + cb + nt * 16 + l15) * 8];   \
    }                                                                          \
    _Pragma("unroll")                                                          \
    for (int mt = 0; mt < 4; mt++){                                            \
      bf16x8 a[8];                                                             \
      _Pragma("unroll")                                                        \
      for (int kk = 0; kk < 8; kk++)                                           \
        a[kk] = *(const bf16x8*)&AIN[(mt * 16 + l15) * LSTR + kk * 32 + quad * 8]; \
      _Pragma("unroll")                                                        \
      for (int kk = 0; kk < 8; kk++)                                           \
        _Pragma("unroll")                                                      \
        for (int nt = 0; nt < 4; nt++)                                         \
          acc[mt][nt] = __builtin_amdgcn_mfma_f32_16x16x32_bf16(               \
              a[kk], CUR[kk][nt], (kk == 0) ? zz : acc[mt][nt], 0, 0, 0);      \
    }                                                                          \
    _Pragma("unroll")                                                          \
    for (int nt = 0; nt < 4; nt++){                                            \
      int col = cb + nt * 16 + l15;                                            \
      float bias = biasb[(L) * 256 + col];                                     \
      _Pragma("unroll")                                                        \
      for (int mt = 0; mt < 4; mt++)                                           \
        _Pragma("unroll")                                                      \
        for (int r = 0; r < 4; r++){                                           \
          float v = acc[mt][nt][r] + bias;                                     \
          v = v > 0.f ? v : 0.f;                                               \
          AOUT[(mt * 16 + quad * 4 + r) * LSTR + col] = f2bf(v);               \
        }                                                                      \
    }                                                                          \
    asm volatile("s_waitcnt lgkmcnt(0)\n\ts_barrier" ::: "memory");            \
  }

  LAYER(1, bregA, bregB, actB, actA, 1)
  LAYER(2, bregB, bregA, actA, actB, 1)
  LAYER(3, bregA, bregB, actB, actA, 1)
  LAYER(4, bregB, bregA, actA, actB, 1)
  LAYER(5, bregA, bregB, actB, actA, 1)
  LAYER(6, bregB, bregA, actA, actB, 0)
#undef LAYER

  // Final layer: (64x256)@(256x2) + sigmoid; layer-6 output is in actB
  {
    int m = tid >> 2;
    int p = tid & 3;
    const unsigned short* hrow = actB + m * LSTR + p * 64;
    const float* wlp = wlb + p * 128;
    float s0 = 0.f, s1 = 0.f;
    #pragma unroll 8
    for (int k = 0; k < 64; k += 2){
      float4 w4 = *(const float4*)&wlp[k * 2];
      unsigned int h2 = *(const unsigned int*)&hrow[k];
      float hv0 = bf2f((unsigned short)(h2 & 0xffff));
      float hv1 = bf2f((unsigned short)(h2 >> 16));
      s0 += hv0 * w4.x + hv1 * w4.z;
      s1 += hv0 * w4.y + hv1 * w4.w;
    }
    s0 += __shfl_xor(s0, 1); s0 += __shfl_xor(s0, 2);
    s1 += __shfl_xor(s1, 1); s1 += __shfl_xor(s1, 2);
    if (p == 0){
      int g = ridx[m];
      if (g >= 0){
        float o0 = 1.f / (1.f + __expf(-(s0 + bl[chart*2+0])));
        float o1 = 1.f / (1.f + __expf(-(s1 + bl[chart*2+1])));
        *(float2*)&out[(size_t)g * 2] = make_float2(o0, o1);
      }
    }
  }
}

// ---- launch ---------------------------------------------------------------

extern "C" void kernel_launch(void* const* d_in, const int* in_sizes, int n_in,
                              void* d_out, int out_size, void* d_ws, size_t ws_size,
                              hipStream_t stream){
  const float* x    = (const float*)d_in[0];
  const float* proc = (const float*)d_in[1];
  const float* W0   = (const float*)d_in[2];
  const float* b0   = (const float*)d_in[3];
  const float* Wh   = (const float*)d_in[4];
  const float* bh   = (const float*)d_in[5];
  const float* Wl   = (const float*)d_in[6];
  const float* bl   = (const float*)d_in[7];
  const int* midx = (const int*)d_in[8];
  float* out = (float*)d_out;

  char* ws = (char*)d_ws;
  int* segcnt = (int*)ws;                           // 8 segs x 8 charts
  int* bucket = segcnt + 64;                        // NCH * SEG ints
  size_t off = (((size_t)(64 + NCH * SEG)) * 4 + 15) & ~(size_t)15;
  unsigned short* Wt0 = (unsigned short*)(ws + off);  // 8 * 8192 bf16
  unsigned short* Wth = Wt0 + NCH * 8192;             // 8 * 6 * 65536 bf16

  hipLaunchKernelGGL(prep_k, dim3(208),  dim3(256), 0, stream,
                     Wh, W0, midx, Wth, Wt0, segcnt, bucket);
  hipLaunchKernelGGL(mlp_k,  dim3(2048), dim3(256), 0, stream,
                     x, proc, b0, bh, Wl, bl, Wt0, Wth, segcnt, bucket, out);
}

// Round 12
// 121.921 us; speedup vs baseline: 1.2141x; 1.2141x over previous
//
#include <hip/hip_runtime.h>
#include <hip/hip_bf16.h>
#include <math.h>

#define NPTS   16384
#define NCH    8
#define MT     32    // rows per block (smaller -> more active blocks/CU)
#define LSTR   264   // act row stride (ushort)
#define SEG    16384 // fixed bucket segment per chart
#define PSEG   2048  // points per scatter sub-segment

typedef short bf16x8 __attribute__((ext_vector_type(8)));
typedef float f32x4  __attribute__((ext_vector_type(4)));

__device__ __forceinline__ float bf2f(unsigned short u){
  union { unsigned int i; float f; } v; v.i = ((unsigned int)u) << 16; return v.f;
}
__device__ __forceinline__ unsigned short f2bf(float f){
  union { float f; unsigned int i; } v; v.f = f;
  unsigned int x = v.i;
  return (unsigned short)((x + 0x7fffu + ((x >> 16) & 1u)) >> 16); // RNE
}

// ---- prep: transpose to k8-major + atomic-free bucketing ------------------

__global__ __launch_bounds__(256) void prep_k(
    const float* __restrict__ Wh, const float* __restrict__ W0,
    const int* __restrict__ midx,
    unsigned short* __restrict__ Wth, unsigned short* __restrict__ Wt0,
    int* __restrict__ segcnt, int* __restrict__ bucket){
  int bid = blockIdx.x, tid = threadIdx.x;
  if (bid < 192){
    __shared__ __align__(16) unsigned short tile[64 * LSTR];
    int mat = bid >> 2, ck = bid & 3;
    const float* src = Wh + (size_t)mat * 65536 + (size_t)ck * 64 * 256;
    int r = tid >> 2, seg = (tid & 3) * 64;
    const float* sp = &src[r * 256 + seg];
    #pragma unroll
    for (int j8 = 0; j8 < 8; j8++){
      float4 f0 = *(const float4*)&sp[j8 * 8];
      float4 f1 = *(const float4*)&sp[j8 * 8 + 4];
      __align__(16) unsigned short t8[8];
      t8[0]=f2bf(f0.x); t8[1]=f2bf(f0.y); t8[2]=f2bf(f0.z); t8[3]=f2bf(f0.w);
      t8[4]=f2bf(f1.x); t8[5]=f2bf(f1.y); t8[6]=f2bf(f1.z); t8[7]=f2bf(f1.w);
      *(uint4*)&tile[r * LSTR + seg + j8 * 8] = *(const uint4*)t8;
    }
    __syncthreads();
    unsigned short* dst = Wth + (size_t)mat * 65536 + (size_t)ck * 16384;
    #pragma unroll
    for (int it = 0; it < 8; it++){
      int s = it * 256 + tid;
      int k8l = s >> 8, n = s & 255;
      __align__(16) unsigned short t8[8];
      #pragma unroll
      for (int j = 0; j < 8; j++) t8[j] = tile[(k8l * 8 + j) * LSTR + n];
      *(uint4*)&dst[(size_t)s * 8] = *(const uint4*)t8;
    }
  } else if (bid < 200){
    int c = bid - 192;
    #pragma unroll
    for (int it = 0; it < 4; it++){
      int s = it * 256 + tid;
      int k8 = s >> 8, n = s & 255;
      __align__(16) unsigned short t8[8];
      #pragma unroll
      for (int j = 0; j < 8; j++){
        int k = k8 * 8 + j;
        t8[j] = (k < 29) ? f2bf(W0[(c * 29 + k) * 256 + n]) : (unsigned short)0;
      }
      *(uint4*)&Wt0[(size_t)c * 8192 + (size_t)s * 8] = *(const uint4*)t8;
    }
  } else {
    __shared__ int cur[NCH];
    int sb = bid - 200;
    int lane = tid & 63;
    if (tid < NCH) cur[tid] = 0;
    __syncthreads();
    for (int it = 0; it < 8; it++){
      int i = sb * PSEG + it * 256 + tid;
      int c = midx[i];
      #pragma unroll
      for (int cc = 0; cc < NCH; cc++){
        unsigned long long m = __ballot(c == cc);
        if (!m) continue;
        int leader = (int)(__ffsll((long long)m) - 1);
        int wb = 0;
        if (lane == leader) wb = atomicAdd(&cur[cc], (int)__popcll(m));
        wb = __shfl(wb, leader);
        if (c == cc){
          int rk = (int)__popcll(m & ((1ull << lane) - 1));
          bucket[cc * SEG + sb * PSEG + wb + rk] = i;
        }
      }
    }
    __syncthreads();
    if (tid < NCH) segcnt[sb * NCH + tid] = cur[tid];
  }
}

// ---- main fused MLP: r10 body (compiler-scheduled), MT=32 for occupancy ---

__global__ __launch_bounds__(256) void mlp_k(
    const float* __restrict__ x,
    const float* __restrict__ proc,
    const float* __restrict__ b0,
    const float* __restrict__ bh,
    const float* __restrict__ Wl,
    const float* __restrict__ bl,
    const unsigned short* __restrict__ Wt0,
    const unsigned short* __restrict__ Wth,
    const int* __restrict__ segcnt,
    const int* __restrict__ bucket,
    float* __restrict__ out)
{
  __shared__ __align__(16) unsigned short actA[MT * LSTR];
  __shared__ __align__(16) unsigned short actB[MT * LSTR];
  __shared__ float biasb[7 * 256];
  __shared__ float wlb[512];
  __shared__ int ridx[MT];

  int chart = blockIdx.x & 7;     // XCD swizzle: chart c pinned to XCD c
  int tile  = blockIdx.x >> 3;

  int pre[9];
  pre[0] = 0;
  #pragma unroll
  for (int s = 0; s < 8; s++) pre[s + 1] = pre[s] + segcnt[s * NCH + chart];
  int total = pre[8];
  int cnt = total - tile * MT;
  if (cnt <= 0) return;
  if (cnt > MT) cnt = MT;

  int tid  = threadIdx.x;
  int lane = tid & 63;
  int wv   = tid >> 6;
  int l15  = lane & 15;
  int quad = lane >> 4;
  int cb   = wv * 64;             // wave's output-column base (N-split)

  // stage biases + Wl
  biasb[tid] = b0[chart * 256 + tid];
  #pragma unroll
  for (int j = 0; j < 6; j++)
    biasb[(j + 1) * 256 + tid] = bh[(chart * 6 + j) * 256 + tid];
  wlb[tid]       = Wl[chart * 512 + tid];
  wlb[256 + tid] = Wl[chart * 512 + 256 + tid];

  // positional encoding -> actA
  if (tid < MT){
    int row = tid;
    int g = -1;
    if (row < cnt){
      int r = tile * MT + row;
      int sb = 0, off = 0;
      #pragma unroll
      for (int s = 0; s < 8; s++)
        if (r >= pre[s]){ sb = s; off = r - pre[s]; }
      g = bucket[chart * SEG + sb * PSEG + off];
    }
    ridx[row] = g;
    unsigned short* rowp = &actA[row * LSTR];
    if (g >= 0){
      float xv0 = x[g*3+0], xv1 = x[g*3+1], xv2 = x[g*3+2];
      rowp[0] = f2bf(xv0); rowp[1] = f2bf(xv1); rowp[2] = f2bf(xv2);
      #pragma unroll
      for (int d = 1; d <= 4; d++){
        float s = (float)(1 << d) * 3.14159265358979323846f;
        int o = 3 + (d - 1) * 6;
        rowp[o+0] = f2bf(sinf(s*xv0)); rowp[o+1] = f2bf(sinf(s*xv1)); rowp[o+2] = f2bf(sinf(s*xv2));
        rowp[o+3] = f2bf(cosf(s*xv0)); rowp[o+4] = f2bf(cosf(s*xv1)); rowp[o+5] = f2bf(cosf(s*xv2));
      }
      rowp[27] = f2bf(proc[0]); rowp[28] = f2bf(proc[1]);
      rowp[29] = 0; rowp[30] = 0; rowp[31] = 0;
    } else {
      #pragma unroll
      for (int k = 0; k < 32; k++) rowp[k] = 0;
    }
  }
  __syncthreads();

  f32x4 acc[2][4];
  const f32x4 zz = {0.f, 0.f, 0.f, 0.f};

  // Layer 0: (32x32)@(32x256); B from Wt0 k8-major (k8 = quad)
  {
    const unsigned short* W0p = Wt0 + chart * 8192;
    bf16x8 b0r[4];
    #pragma unroll
    for (int nt = 0; nt < 4; nt++)
      b0r[nt] = *(const bf16x8*)&W0p[(size_t)(quad * 256 + cb + nt * 16 + l15) * 8];
    #pragma unroll
    for (int mt = 0; mt < 2; mt++){
      bf16x8 a0 = *(const bf16x8*)&actA[(mt * 16 + l15) * LSTR + quad * 8];
      #pragma unroll
      for (int nt = 0; nt < 4; nt++)
        acc[mt][nt] = __builtin_amdgcn_mfma_f32_16x16x32_bf16(a0, b0r[nt], zz, 0, 0, 0);
    }
    #pragma unroll
    for (int nt = 0; nt < 4; nt++){
      int col = cb + nt * 16 + l15;
      float bias = biasb[col];
      #pragma unroll
      for (int mt = 0; mt < 2; mt++)
        #pragma unroll
        for (int r = 0; r < 4; r++){
          float v = acc[mt][nt][r] + bias;
          v = v > 0.f ? v : 0.f;
          actB[(mt * 16 + quad * 4 + r) * LSTR + col] = f2bf(v);
        }
    }
  }
  __syncthreads();

  // 6 hidden layers: per-layer B slab (32 x 16B, k8-major contiguous)
  for (int l = 1; l <= 6; l++){
    const unsigned short* wl8 = Wth + ((size_t)(chart * 6 + l - 1) << 16);
    const unsigned short* ain = (l & 1) ? actB : actA;
    unsigned short* aout      = (l & 1) ? actA : actB;

    bf16x8 breg[8][4];
    #pragma unroll
    for (int kk = 0; kk < 8; kk++)
      #pragma unroll
      for (int nt = 0; nt < 4; nt++)
        breg[kk][nt] = *(const bf16x8*)
            &wl8[(size_t)((kk * 4 + quad) * 256 + cb + nt * 16 + l15) * 8];

    #pragma unroll
    for (int mt = 0; mt < 2; mt++){
      bf16x8 a[8];
      #pragma unroll
      for (int kk = 0; kk < 8; kk++)
        a[kk] = *(const bf16x8*)&ain[(mt * 16 + l15) * LSTR + kk * 32 + quad * 8];
      #pragma unroll
      for (int kk = 0; kk < 8; kk++)
        #pragma unroll
        for (int nt = 0; nt < 4; nt++)
          acc[mt][nt] = __builtin_amdgcn_mfma_f32_16x16x32_bf16(
              a[kk], breg[kk][nt], (kk == 0) ? zz : acc[mt][nt], 0, 0, 0);
    }

    #pragma unroll
    for (int nt = 0; nt < 4; nt++){
      int col = cb + nt * 16 + l15;
      float bias = biasb[l * 256 + col];
      #pragma unroll
      for (int mt = 0; mt < 2; mt++)
        #pragma unroll
        for (int r = 0; r < 4; r++){
          float v = acc[mt][nt][r] + bias;
          v = v > 0.f ? v : 0.f;
          aout[(mt * 16 + quad * 4 + r) * LSTR + col] = f2bf(v);
        }
    }
    __syncthreads();
  }

  // Final layer: (32x256)@(256x2) + sigmoid.
  // Parity: L0->actB, L1->actA, ..., L6->actB  => layer-6 output in actB.
  {
    int m = tid >> 3;          // 0..31 rows
    int p = tid & 7;           // 8 threads/row, 32 k each
    const unsigned short* hrow = actB + m * LSTR + p * 32;
    const float* wlp = wlb + p * 64;
    float s0 = 0.f, s1 = 0.f;
    #pragma unroll 8
    for (int k = 0; k < 32; k += 2){
      float4 w4 = *(const float4*)&wlp[k * 2];
      unsigned int h2 = *(const unsigned int*)&hrow[k];
      float hv0 = bf2f((unsigned short)(h2 & 0xffff));
      float hv1 = bf2f((unsigned short)(h2 >> 16));
      s0 += hv0 * w4.x + hv1 * w4.z;
      s1 += hv0 * w4.y + hv1 * w4.w;
    }
    s0 += __shfl_xor(s0, 1); s0 += __shfl_xor(s0, 2); s0 += __shfl_xor(s0, 4);
    s1 += __shfl_xor(s1, 1); s1 += __shfl_xor(s1, 2); s1 += __shfl_xor(s1, 4);
    if (p == 0){
      int g = ridx[m];
      if (g >= 0){
        float o0 = 1.f / (1.f + __expf(-(s0 + bl[chart*2+0])));
        float o1 = 1.f / (1.f + __expf(-(s1 + bl[chart*2+1])));
        *(float2*)&out[(size_t)g * 2] = make_float2(o0, o1);
      }
    }
  }
}

// ---- launch ---------------------------------------------------------------

extern "C" void kernel_launch(void* const* d_in, const int* in_sizes, int n_in,
                              void* d_out, int out_size, void* d_ws, size_t ws_size,
                              hipStream_t stream){
  const float* x    = (const float*)d_in[0];
  const float* proc = (const float*)d_in[1];
  const float* W0   = (const float*)d_in[2];
  const float* b0   = (const float*)d_in[3];
  const float* Wh   = (const float*)d_in[4];
  const float* bh   = (const float*)d_in[5];
  const float* Wl   = (const float*)d_in[6];
  const float* bl   = (const float*)d_in[7];
  const int* midx = (const int*)d_in[8];
  float* out = (float*)d_out;

  char* ws = (char*)d_ws;
  int* segcnt = (int*)ws;                           // 8 segs x 8 charts
  int* bucket = segcnt + 64;                        // NCH * SEG ints
  size_t off = (((size_t)(64 + NCH * SEG)) * 4 + 15) & ~(size_t)15;
  unsigned short* Wt0 = (unsigned short*)(ws + off);  // 8 * 8192 bf16
  unsigned short* Wth = Wt0 + NCH * 8192;             // 8 * 6 * 65536 bf16

  hipLaunchKernelGGL(prep_k, dim3(208),  dim3(256), 0, stream,
                     Wh, W0, midx, Wth, Wt0, segcnt, bucket);
  hipLaunchKernelGGL(mlp_k,  dim3(4096), dim3(256), 0, stream,
                     x, proc, b0, bh, Wl, bl, Wt0, Wth, segcnt, bucket, out);
}